// Round 1
// baseline (164.920 us; speedup 1.0000x reference)
//
#include <hip/hip_runtime.h>
#include <stdint.h>

#define TPB 256
#define BB  128
#define SS  512
#define LLW 20
#define NN  (BB * SS * LLW)   // 1,310,720
#define KPT 2                 // k's per thread
#define KPB (TPB * KPT)       // 512 k's per block
#define NBLK (NN / KPB)       // 2560 blocks

// ---------------- pre-kernel: one block computes the shared tables ----------
// ws layout (ints): [0..127] inclusive prefix viable-counts C
//                   [128..255] lens copy, [256] max(lens)
__global__ __launch_bounds__(BB) void span_pre(const int* __restrict__ lens,
                                               int* __restrict__ ws) {
  __shared__ int sC[BB], sM[BB];
  const int t = threadIdx.x;
  const int len = lens[t];
  sC[t] = LLW * len - (LLW * (LLW - 1)) / 2;   // count(b); len >= L guaranteed
  sM[t] = len;
  for (int off = 1; off < BB; off <<= 1) {
    __syncthreads();
    int aC = sC[t]; int bC = (t >= off) ? sC[t - off] : 0;
    int aM = sM[t]; int bM = sM[t ^ off];
    __syncthreads();
    sC[t] = aC + bC;
    sM[t] = (aM > bM) ? aM : bM;
  }
  __syncthreads();
  ws[t]      = sC[t];
  ws[BB + t] = len;
  if (t == 0) ws[2 * BB] = sM[0];
}

static __device__ __forceinline__ int batch_of(int k, const int* shC) {
  int lo = 0, hi = BB - 1;
  while (lo < hi) {            // smallest b with inclusive count > k
    int mid = (lo + hi) >> 1;
    if (shC[mid] > k) hi = mid; else lo = mid + 1;
  }
  return lo;
}

// Invert compacted index k -> (b, s, j). k >= K gives pad (0,0,0).
static __device__ __forceinline__ void invert(int k, const int* shC,
                                              const int* shLen, int K,
                                              int* pb, int* ps, int* pj) {
  int b = 0, s = 0, j = 0;
  if (k < K) {
    b = batch_of(k, shC);
    int base = (b == 0) ? 0 : shC[b - 1];
    int m    = k - base;
    int lenb = shLen[b];
    int full = LLW * (lenb - LLW + 1);   // rows with all L spans viable
    if (m < full) {
      s = m / LLW;
      j = m - s * LLW;
    } else {                             // triangular tail; row s has len_b - s spans
      int Cb = shC[b] - base;
      int tt = Cb - m;                   // in (r(r-1)/2, r(r+1)/2], r = lenb - s
      float rf = (sqrtf(8.0f * (float)tt + 1.0f) - 1.0f) * 0.5f;
      int r = (int)(rf + 0.5f);
      if (r * (r + 1) / 2 < tt) r++;
      if (r > 1 && r * (r - 1) / 2 >= tt) r--;
      s = lenb - r;
      j = r * (r + 1) / 2 - tt;
    }
  }
  *pb = b; *ps = s; *pj = j;
}

// d_out is FLOAT32. Return-order layout, offsets in units of NN:
//   0 viable | 1 batch | 2 starts | 3 ends | 4 lengths | 5..24 units
//   25 p_weights | 26 start_cand | 27 end_cand | 28 len_cand
__global__ __launch_bounds__(TPB, 4) void span_main(
    const int* __restrict__ seqs,    // [B*S] int32
    const float* __restrict__ pw,    // [B*S*L] f32
    const int* __restrict__ ws,      // precomputed tables
    float* __restrict__ out) {
  __shared__ int shC[BB], shLen[BB];
  __shared__ int sBS[KPB];                 // packed (b<<16)|s per local k
  const int t = threadIdx.x;
  if (t < BB) { shC[t] = ws[t]; shLen[t] = ws[BB + t]; }
  const int K  = ws[BB - 1];               // uniform -> s_load
  const int ml = ws[2 * BB];               // uniform -> s_load
  __syncthreads();

  const int gid    = blockIdx.x * TPB + t;
  const int k0     = gid * KPT;            // this thread's first k / f
  const int blk_k0 = blockIdx.x * KPB;
  const size_t Nz  = (size_t)NN;

  // ---- phase 1b: compacted scalars, invert once + incremental stepping ----
  {
    int b, s, j;
    invert(k0, shC, shLen, K, &b, &s, &j);
    float qb[KPT], qs[KPT], qe[KPT], ql[KPT], qp[KPT];
#pragma unroll
    for (int i = 0; i < KPT; i++) {
      int ki = k0 + i;
      int vb = 0, vs = 0, vj = 0;
      if (ki < K) {
        vb = b; vs = s; vj = j;
        j++;                                  // advance to next k
        int lenb = shLen[b];
        int cs = lenb - s; if (cs > LLW) cs = LLW;
        if (j >= cs) { j = 0; s++; if (s >= lenb) { s = 0; b++; } }
      }
      qb[i] = (float)vb; qs[i] = (float)vs;
      qe[i] = (float)(vs + vj); ql[i] = (float)(vj + 1);
      qp[i] = pw[((size_t)vb * SS + vs) * LLW + vj];
      sBS[t * KPT + i] = (vb << 16) | vs;
    }
    *(float2*)(out + Nz + k0)      = make_float2(qb[0], qb[1]);
    *(float2*)(out + 2 * Nz + k0)  = make_float2(qs[0], qs[1]);
    *(float2*)(out + 3 * Nz + k0)  = make_float2(qe[0], qe[1]);
    *(float2*)(out + 4 * Nz + k0)  = make_float2(ql[0], ql[1]);
    *(float2*)(out + 25 * Nz + k0) = make_float2(qp[0], qp[1]);
  }
  __syncthreads();                           // sBS ready for phase 2

  // ---- phase 1a: candidate-indexed outputs (pure function of index) -------
  {
    float qv[KPT], qsc[KPT], qec[KPT], qlc[KPT];
#pragma unroll
    for (int i = 0; i < KPT; i++) {
      int f   = k0 + i;
      int row = f / LLW;
      int jj  = f - row * LLW;
      int b2  = row >> 9;        // row / SS
      int s2  = row & (SS - 1);  // row % SS
      int e2  = s2 + jj;
      qv[i]  = (e2 < shLen[b2]) ? 1.0f : 0.0f;
      qsc[i] = (float)s2; qec[i] = (float)e2; qlc[i] = (float)(jj + 1);
    }
    *(float2*)(out + k0)           = make_float2(qv[0], qv[1]);
    *(float2*)(out + 26 * Nz + k0) = make_float2(qsc[0], qsc[1]);
    *(float2*)(out + 27 * Nz + k0) = make_float2(qec[0], qec[1]);
    *(float2*)(out + 28 * Nz + k0) = make_float2(qlc[0], qlc[1]);
  }

  // ---- phase 2: units region straight from L1/L2 (seqs is 256 KB, resident)
  // Block span = 512 rows x 20 floats = 2560 float4 chunks (40 KB contiguous).
  {
    const int ml1 = ml - 1;
    float4* udst = (float4*)(out + 5 * Nz + (size_t)blk_k0 * LLW);
    for (int c = 0; c < (KPB * (LLW / 4)) / TPB; c++) {   // 10 iterations
      int chunk = t + c * TPB;
      int krow  = chunk / 5;
      int e0    = (chunk - krow * 5) << 2;
      int bs    = sBS[krow];
      int b = bs >> 16, s = bs & 0xFFFF;
      const int* rp = seqs + (size_t)b * SS;
      int p0 = s + e0;     if (p0 > ml1) p0 = ml1;
      int p1 = s + e0 + 1; if (p1 > ml1) p1 = ml1;
      int p2 = s + e0 + 2; if (p2 > ml1) p2 = ml1;
      int p3 = s + e0 + 3; if (p3 > ml1) p3 = ml1;
      float4 v;
      v.x = (float)rp[p0]; v.y = (float)rp[p1];
      v.z = (float)rp[p2]; v.w = (float)rp[p3];
      udst[chunk] = v;
    }
  }
}

extern "C" void kernel_launch(void* const* d_in, const int* in_sizes, int n_in,
                              void* d_out, int out_size, void* d_ws, size_t ws_size,
                              hipStream_t stream) {
  const int*   seqs = (const int*)d_in[0];    // lost_unit_id_seqs [128,512]
  const int*   lens = (const int*)d_in[1];    // lost_lengths [128]
  const float* pw   = (const float*)d_in[2];  // p_weights [128,512,20]
  float* out = (float*)d_out;
  int*   ws  = (int*)d_ws;

  span_pre<<<1, BB, 0, stream>>>(lens, ws);
  span_main<<<NBLK, TPB, 0, stream>>>(seqs, pw, (const int*)ws, out);
}